// Round 1
// baseline (8864.802 us; speedup 1.0000x reference)
//
#include <hip/hip_runtime.h>
#include <math.h>

// Problem constants
#define B_    2
#define C_    128
#define H_    512
#define W_    512
#define NWIN  4096      // 64*64 windows per batch
#define NWF   1228      // int(4096*0.3)
#define NSEL  (B_*NWF)  // 2456
#define SCALE 0.08838834764831845f  // 128^-0.5

__device__ __forceinline__ float wave_max64(float v){
  #pragma unroll
  for (int off = 32; off; off >>= 1) v = fmaxf(v, __shfl_xor(v, off, 64));
  return v;
}
__device__ __forceinline__ float wave_sum64(float v){
  #pragma unroll
  for (int off = 32; off; off >>= 1) v += __shfl_xor(v, off, 64);
  return v;
}
__device__ __forceinline__ float gelu_f(float x){
  return 0.5f * x * (1.0f + erff(x * 0.70710678118654752440f));
}

// ---------------- window scores: mean of uncertainty per 8x8 window ----------
__global__ void score_k(const float* __restrict__ unc, float* __restrict__ scores){
  int win = blockIdx.x;            // b*4096 + ih*64 + iw
  int b = win >> 12, w12 = win & 4095;
  int ih = w12 >> 6, iw = w12 & 63;
  int t = threadIdx.x, r = t >> 3, s = t & 7;
  float v = unc[((size_t)b*512 + ih*8 + r)*512 + iw*8 + s];
  v = wave_sum64(v);
  if (t == 0) scores[win] = v * (1.0f/64.0f);
}

// ---------------- top-k selection via exact rank (ties -> lower index) -------
__global__ void select_k(const float* __restrict__ scores, int* __restrict__ sel){
  int b = blockIdx.x;
  __shared__ float s[NWIN];
  for (int i = threadIdx.x; i < NWIN; i += 1024) s[i] = scores[b*NWIN + i];
  __syncthreads();
  for (int w = threadIdx.x; w < NWIN; w += 1024){
    float mys = s[w];
    int rank = 0;
    for (int j2 = 0; j2 < NWIN; ++j2){
      float o = s[j2];
      rank += (o > mys) || (o == mys && j2 < w);
    }
    if (rank < NWF) sel[b*NWF + rank] = w;
  }
}

// ---------------- 64x64-block pooling -> g[b][p][c]  (p = i*8+k) -------------
__global__ void pool_k(const float* __restrict__ fm, float* __restrict__ g){
  int id = blockIdx.x;             // (b*128 + c)*64 + p, 16384 blocks
  int p = id & 63, c = (id >> 6) & 127, b = id >> 13;
  int i = p >> 3, k = p & 7;
  const float* base = fm + (((size_t)b*128 + c)*512 + i*64)*512 + k*64;
  int tid = threadIdx.x;
  float sum = 0.0f;
  #pragma unroll
  for (int it = 0; it < 16; ++it){
    int f = it*256 + tid;
    int j2 = f >> 6, l = f & 63;
    sum += base[(size_t)j2*512 + l];
  }
  __shared__ float red[256];
  red[tid] = sum; __syncthreads();
  for (int s2 = 128; s2; s2 >>= 1){
    if (tid < s2) red[tid] += red[tid + s2];
    __syncthreads();
  }
  if (tid == 0) g[((b*64 + p) << 7) + c] = red[0] * (1.0f/4096.0f);
}

// ---------------- k,v = g @ kv_g_w.T -----------------------------------------
__global__ void kv_k(const float* __restrict__ g, const float* __restrict__ kvw,
                     float* __restrict__ kbuf, float* __restrict__ vbuf){
  int gid = blockIdx.x*256 + threadIdx.x;   // B*64*128 = 16384
  int c = gid & 127, p = (gid >> 7) & 63, b = gid >> 13;
  const float* grow = g + ((b*64 + p) << 7);
  const float* wk = kvw + (c << 7);
  const float* wv = kvw + ((128 + c) << 7);
  float ka = 0.0f, va = 0.0f;
  #pragma unroll 8
  for (int d = 0; d < 128; ++d){ float gv = grow[d]; ka += gv*wk[d]; va += gv*wv[d]; }
  kbuf[gid] = ka; vbuf[gid] = va;
}

// ---------------- Mb = k_b @ q_g_w  (folds q-proj into attn1 scores) ---------
__global__ void mb_k(const float* __restrict__ kbuf, const float* __restrict__ qgw,
                     float* __restrict__ Mb){
  int gid = blockIdx.x*256 + threadIdx.x;   // B*64*128
  int d = gid & 127, p = (gid >> 7) & 63, b = gid >> 13;
  const float* krow = kbuf + ((b*64 + p) << 7);
  float acc = 0.0f;
  #pragma unroll 8
  for (int c = 0; c < 128; ++c) acc += krow[c] * qgw[(c << 7) + d];
  Mb[gid] = acc;
}

// ---------------- M2T[e][d] = sum_c Wq2[c][d] * Wk2[c][e] --------------------
__global__ void m2t_k(const float* __restrict__ qkvw, float* __restrict__ M2T){
  int gid = blockIdx.x*256 + threadIdx.x;   // 128*128
  int d = gid & 127, e = gid >> 7;
  float acc = 0.0f;
  #pragma unroll 8
  for (int c = 0; c < 128; ++c) acc += qkvw[(c << 7) + d] * qkvw[((128 + c) << 7) + e];
  M2T[gid] = acc;
}

// ---------------- megakernel: attn1 + MLP1 + attn2(+quirk) + MLP2 + scatter --
// LDS swizzle: element (t,c) -> t*128 + ((c+t)&127)  (kills stride-128 conflicts)
#define WF(t,c) wf_s[((t)<<7) + (((c)+(t)) & 127)]
#define AX(t,c) aux_s[((t)<<7) + (((c)+(t)) & 127)]

__global__ __launch_bounds__(256) void mega_k(
    const float* __restrict__ fm, const int* __restrict__ sel,
    const float* __restrict__ Mb, const float* __restrict__ vbuf,
    const float* __restrict__ M2T, const float* __restrict__ qkvw,
    const float* __restrict__ l0w, const float* __restrict__ l0b,
    const float* __restrict__ pw,  const float* __restrict__ pb,
    float* __restrict__ out)
{
  __shared__ float wf_s[64*128];   // 32 KB
  __shared__ float aux_s[64*128];  // 32 KB
  const int tid = threadIdx.x, lane = tid & 63, wv = tid >> 6;
  const int j = blockIdx.x;                 // 0..2455
  const int b = j / NWF;
  const int win = sel[j];
  const int ih = win >> 6, iw = win & 63;

  // P1: gather window tokens  wf[t][c] = fm[b,c,ih*8+r,iw*8+s]
  {
    const float* fmb = fm + ((size_t)b*128)*512*512;
    #pragma unroll
    for (int it = 0; it < 32; ++it){
      int flat = it*256 + tid;          // flat = c*64 + t (coalesced in w)
      int c = flat >> 6, t = flat & 63;
      int r = t >> 3, s = t & 7;
      WF(t,c) = fmb[((size_t)c*512 + ih*8 + r)*512 + iw*8 + s];
    }
  }
  __syncthreads();

  // P2: attn1 — S1[t,p] = scale * sum_d wf[t,d]*Mb[b,p,d]; softmax over p;
  //     wf[t,:] += P @ v_b.  Row t handled entirely by one wave.
  {
    const float* vb = vbuf + ((size_t)(b*64) << 7);
    for (int rr = 0; rr < 16; ++rr){
      int t = wv*16 + rr;
      const float* mbrow = Mb + (((size_t)b*64 + lane) << 7);
      float acc = 0.0f;
      #pragma unroll 8
      for (int d = 0; d < 128; ++d) acc += WF(t,d) * mbrow[d];
      acc *= SCALE;
      float m = wave_max64(acc);
      float e = __expf(acc - m);
      float p = e / wave_sum64(e);
      float a0 = 0.0f, a1 = 0.0f;
      #pragma unroll 8
      for (int l2 = 0; l2 < 64; ++l2){
        float pl = __shfl(p, l2, 64);
        a0 += pl * vb[(l2 << 7) + lane];
        a1 += pl * vb[(l2 << 7) + lane + 64];
      }
      WF(t,lane)    += a0;
      WF(t,lane+64) += a1;
    }
  }
  __syncthreads();

  // P3: MLP1  wf += gelu(wf @ l0w^T + l0b)
  {
    float hreg[32];
    #pragma unroll
    for (int it = 0; it < 32; ++it){
      int flat = it*256 + tid;
      int t = flat >> 7, c = flat & 127;
      const float* wrow = l0w + (c << 7);
      float acc = l0b[c];
      #pragma unroll 8
      for (int d = 0; d < 128; ++d) acc += WF(t,d) * wrow[d];
      hreg[it] = gelu_f(acc);
    }
    __syncthreads();
    #pragma unroll
    for (int it = 0; it < 32; ++it){
      int flat = it*256 + tid;
      int t = flat >> 7, c = flat & 127;
      WF(t,c) += hreg[it];
    }
  }
  __syncthreads();

  // P4: T = wf @ M2  -> aux   (T[t,e] = sum_d wf[t,d] * M2T[e,d])
  #pragma unroll
  for (int it = 0; it < 32; ++it){
    int flat = it*256 + tid;
    int t = flat >> 7, e = flat & 127;
    const float* mrow = M2T + (e << 7);
    float acc = 0.0f;
    #pragma unroll 8
    for (int d = 0; d < 128; ++d) acc += WF(t,d) * mrow[d];
    AX(t,e) = acc;
  }
  __syncthreads();

  // P5: attn2 — S2[t,t'] = scale * sum_e T[t,e]*wf[t',e]; softmax;
  //     U[t,:] = P @ wf  overwrites aux row t (each wave owns its rows)
  for (int rr = 0; rr < 16; ++rr){
    int t = wv*16 + rr;
    float acc = 0.0f;
    #pragma unroll 8
    for (int e = 0; e < 128; ++e) acc += AX(t,e) * WF(lane,e);
    acc *= SCALE;
    float m = wave_max64(acc);
    float e2 = __expf(acc - m);
    float p = e2 / wave_sum64(e2);
    float u0 = 0.0f, u1 = 0.0f;
    #pragma unroll 8
    for (int l2 = 0; l2 < 64; ++l2){
      float pl = __shfl(p, l2, 64);
      u0 += pl * WF(l2, lane);
      u1 += pl * WF(l2, lane + 64);
    }
    AX(t,lane)    = u0;
    AX(t,lane+64) = u1;
  }
  __syncthreads();

  // P6: av2 = U @ Wv2^T with the reference's swapaxes(1,2).reshape quirk:
  //     wf[t,c] += av[(t*128+c)%64, (t*128+c)/64]
  //     i.e. for av[q,cp]: flat2 = cp*64+q -> target (flat2>>7, flat2&127)
  #pragma unroll
  for (int it = 0; it < 32; ++it){
    int flat = it*256 + tid;
    int q = flat >> 7, cp = flat & 127;
    const float* wrow = qkvw + ((size_t)(256 + cp) << 7);
    float acc = 0.0f;
    #pragma unroll 8
    for (int d = 0; d < 128; ++d) acc += AX(q,d) * wrow[d];
    int flat2 = cp*64 + q;
    WF(flat2 >> 7, flat2 & 127) += acc;   // bijective target, no race
  }
  __syncthreads();

  // P7: MLP2  wf += gelu(wf @ pw^T + pb)
  {
    float hreg[32];
    #pragma unroll
    for (int it = 0; it < 32; ++it){
      int flat = it*256 + tid;
      int t = flat >> 7, c = flat & 127;
      const float* wrow = pw + (c << 7);
      float acc = pb[c];
      #pragma unroll 8
      for (int d = 0; d < 128; ++d) acc += WF(t,d) * wrow[d];
      hreg[it] = gelu_f(acc);
    }
    __syncthreads();
    #pragma unroll
    for (int it = 0; it < 32; ++it){
      int flat = it*256 + tid;
      int t = flat >> 7, c = flat & 127;
      WF(t,c) += hreg[it];
    }
  }
  __syncthreads();

  // P8: scatter back into out (pass-through copy already done)
  {
    float* outb = out + ((size_t)b*128)*512*512;
    #pragma unroll
    for (int it = 0; it < 32; ++it){
      int flat = it*256 + tid;
      int c = flat >> 6, t = flat & 63;
      int r = t >> 3, s = t & 7;
      outb[((size_t)c*512 + ih*8 + r)*512 + iw*8 + s] = WF(t,c);
    }
  }
}
#undef WF
#undef AX

extern "C" void kernel_launch(void* const* d_in, const int* in_sizes, int n_in,
                              void* d_out, int out_size, void* d_ws, size_t ws_size,
                              hipStream_t stream) {
  const float* fm   = (const float*)d_in[0];
  const float* unc  = (const float*)d_in[1];
  const float* qgw  = (const float*)d_in[2];
  const float* kvw  = (const float*)d_in[3];
  const float* l0w  = (const float*)d_in[4];
  const float* l0b  = (const float*)d_in[5];
  const float* qkvw = (const float*)d_in[6];
  const float* pw   = (const float*)d_in[7];
  const float* pb   = (const float*)d_in[8];
  float* out = (float*)d_out;

  float* ws     = (float*)d_ws;
  float* scores = ws;                    // 8192
  int*   sel    = (int*)(ws + 8192);     // 2456 (padded to 4096)
  float* g      = ws + 12288;            // 16384
  float* kbuf   = ws + 28672;            // 16384
  float* vbuf   = ws + 45056;            // 16384
  float* Mb     = ws + 61440;            // 16384
  float* M2T    = ws + 77824;            // 16384  (end: 94208 floats ~368 KB)

  // pass-through copy: out = feature_map (selected windows overwritten later)
  hipMemcpyAsync(out, fm, (size_t)B_*C_*H_*W_*sizeof(float),
                 hipMemcpyDeviceToDevice, stream);

  score_k <<<B_*NWIN, 64, 0, stream>>>(unc, scores);
  select_k<<<B_, 1024, 0, stream>>>(scores, sel);
  pool_k  <<<B_*C_*64, 256, 0, stream>>>(fm, g);
  kv_k    <<<64, 256, 0, stream>>>(g, kvw, kbuf, vbuf);
  mb_k    <<<64, 256, 0, stream>>>(kbuf, qgw, Mb);
  m2t_k   <<<64, 256, 0, stream>>>(qkvw, M2T);
  mega_k  <<<NSEL, 256, 0, stream>>>(fm, sel, Mb, vbuf, M2T, qkvw,
                                     l0w, l0b, pw, pb, out);
}